// Round 1
// 851.277 us; speedup vs baseline: 1.0949x; 1.0949x over previous
//
#include <hip/hip_runtime.h>

#define NB   32      // batch
#define DIM  4096
#define HQ   32
#define HKV  8
#define HD   128
#define MAXS 2048

#define TSPLIT 4
#define CH   (MAXS / TSPLIT)   // 512

// ---------------------------------------------------------------------------
// GEMV-32: C[b, r] += sum_k W[r,k] * X[b,k]   for 32 batch rows at once.
// Grid: (M/64, KSPLIT). Each block: 64 rows x 32 b, K-slice of K/KSPLIT.
// Partials combined via fp32 atomicAdd (targets pre-zeroed).
// ---------------------------------------------------------------------------
__global__ __launch_bounds__(256)
void gemv32(const float* __restrict__ W, const float* __restrict__ X,
            float* __restrict__ C, int K, long strideB)
{
    __shared__ __align__(16) float xs[32][68];   // +4 pad: conflict-free
    __shared__ __align__(16) float wt[64][68];
    const int tid = threadIdx.x;
    const int bg  = tid & 7;          // 8 b-groups, b = bg + 8j
    const int mg  = tid >> 3;         // 0..31 -> rows 2mg, 2mg+1
    const int row0 = blockIdx.x * 64;
    const int ks   = K / gridDim.y;
    const int kbeg = blockIdx.y * ks;
    const int kend = kbeg + ks;

    float acc[2][4] = {};

    for (int k0 = kbeg; k0 < kend; k0 += 64) {
        // stage X tile (32 x 64)
        for (int i = tid; i < 32 * 16; i += 256) {
            int b = i >> 4, kq = i & 15;
            float4 v = *(const float4*)(X + (long)b * K + k0 + kq * 4);
            *(float4*)&xs[b][kq * 4] = v;
        }
        // stage W tile (64 x 64)
        for (int i = tid; i < 64 * 16; i += 256) {
            int m = i >> 4, kq = i & 15;
            float4 v = *(const float4*)(W + (long)(row0 + m) * K + k0 + kq * 4);
            *(float4*)&wt[m][kq * 4] = v;
        }
        __syncthreads();
        #pragma unroll
        for (int kq = 0; kq < 16; ++kq) {
            float4 w0 = *(const float4*)&wt[mg * 2 + 0][kq * 4];
            float4 w1 = *(const float4*)&wt[mg * 2 + 1][kq * 4];
            #pragma unroll
            for (int j = 0; j < 4; ++j) {
                float4 xv = *(const float4*)&xs[bg + 8 * j][kq * 4];
                acc[0][j] = fmaf(w0.x, xv.x, acc[0][j]);
                acc[0][j] = fmaf(w0.y, xv.y, acc[0][j]);
                acc[0][j] = fmaf(w0.z, xv.z, acc[0][j]);
                acc[0][j] = fmaf(w0.w, xv.w, acc[0][j]);
                acc[1][j] = fmaf(w1.x, xv.x, acc[1][j]);
                acc[1][j] = fmaf(w1.y, xv.y, acc[1][j]);
                acc[1][j] = fmaf(w1.z, xv.z, acc[1][j]);
                acc[1][j] = fmaf(w1.w, xv.w, acc[1][j]);
            }
        }
        __syncthreads();
    }
    #pragma unroll
    for (int j = 0; j < 4; ++j) {
        int b = bg + 8 * j;
        atomicAdd(&C[(long)b * strideB + row0 + mg * 2 + 0], acc[0][j]);
        atomicAdd(&C[(long)b * strideB + row0 + mg * 2 + 1], acc[1][j]);
    }
}

// ---------------------------------------------------------------------------
// RoPE on q (in-place) and k (k_new -> k_cache[b][start]), copy v into cache.
// Flat grid-stride over all three jobs (launch with 256 blocks, not 32:
// 32 blocks left 224 CUs idle).
// ---------------------------------------------------------------------------
__global__ __launch_bounds__(256)
void rope_scatter(float* __restrict__ q_buf, const float* __restrict__ k_new,
                  const float* __restrict__ v_new, float* __restrict__ k_cache,
                  float* __restrict__ v_cache, const float* __restrict__ fc,
                  const float* __restrict__ fs, const int* __restrict__ sp)
{
    const int start = sp[0];
    const int gt = blockIdx.x * 256 + threadIdx.x;
    const int NT = gridDim.x * 256;

    // q rope: NB*HQ*64 = 65536 pairs; pair i -> offset 2*i within batch row
    for (int i = gt; i < NB * HQ * 64; i += NT) {
        int b = i >> 11, r = i & 2047, p = r & 63;
        float c = fc[p], s = fs[p];
        float2 xv = *(float2*)(q_buf + (long)b * DIM + 2 * r);
        float2 ov = make_float2(xv.x * c - xv.y * s, xv.x * s + xv.y * c);
        *(float2*)(q_buf + (long)b * DIM + 2 * r) = ov;
    }
    // k rope + scatter: NB*HKV*64 = 16384 pairs
    for (int i = gt; i < NB * HKV * 64; i += NT) {
        int b = i >> 9, r = i & 511, p = r & 63;
        float c = fc[p], s = fs[p];
        float2 xv = *(const float2*)(k_new + (long)b * (HKV * HD) + 2 * r);
        float2 ov = make_float2(xv.x * c - xv.y * s, xv.x * s + xv.y * c);
        *(float2*)(k_cache + ((long)b * MAXS + start) * (HKV * HD) + 2 * r) = ov;
    }
    // v scatter: NB*HKV*HD/4 = 8192 float4
    for (int i = gt; i < NB * HKV * HD / 4; i += NT) {
        int b = i >> 8, j = i & 255;
        float4 v = *(const float4*)(v_new + (long)b * (HKV * HD) + 4 * j);
        *(float4*)(v_cache + ((long)b * MAXS + start) * (HKV * HD) + 4 * j) = v;
    }
}

// ---------------------------------------------------------------------------
// Flash-decoding attention, partial pass. One block per (kv-group g, batch b,
// T-chunk ts). 512 threads = 8 waves; chunk = CH=512 positions.
// Writes unnormalized O-partial plus per-head (m, l) for the chunk.
// 1024 blocks -> 4 blocks/CU -> ~32 waves/CU (was 8).
// ---------------------------------------------------------------------------
__global__ __launch_bounds__(512)
void attention_part(const float* __restrict__ q_buf,
                    const float* __restrict__ k_cache,
                    const float* __restrict__ v_cache,
                    float* __restrict__ part_o,    // [NB][HKV][TSPLIT][4][HD]
                    float2* __restrict__ part_ml,  // [NB][HKV][TSPLIT][4]
                    const int* __restrict__ sp)
{
    const int g = blockIdx.x, b = blockIdx.y, ts = blockIdx.z;
    const int tid = threadIdx.x;
    const int wave = tid >> 6, lane = tid & 63;
    const int L = sp[0] + 1;          // 2048
    const int tbeg = ts * CH;

    __shared__ __align__(16) float qs[4 * HD];        // 2 KB
    __shared__ __align__(16) float sc[4][CH];         // 8 KB
    __shared__ __align__(16) float outred[16 * HD];   // 8 KB
    __shared__ float wred[8];
    __shared__ float m_sh[4], l_sh[4];

    for (int i = tid; i < 4 * HD; i += 512)
        qs[i] = q_buf[(long)b * DIM + g * 4 * HD + i];
    __syncthreads();

    const float scale = 0.08838834764831845f;  // 1/sqrt(128)
    const float* Kbase = k_cache + ((long)b * MAXS * HKV + g) * HD;

    // ---- pass 1: scores for CH positions, 4 heads ----------------------
    {
        const int r = lane & 3, tr = lane >> 2;   // head, t-row within group
        #pragma unroll
        for (int grp = 0; grp < CH / 128; ++grp) {        // 4
            int tl = wave * (CH / 8) + grp * 16 + tr;     // local t in [0,CH)
            int t  = tbeg + tl;                           // global t < MAXS
            const float* Kt = Kbase + (long)t * (HKV * HD);
            float a0 = 0.f, a1 = 0.f;
            #pragma unroll
            for (int kq = 0; kq < 16; ++kq) {
                float4 kv = *(const float4*)(Kt + kq * 4);
                float4 qv = *(const float4*)(qs + r * HD + kq * 4);
                a0 = fmaf(kv.x, qv.x, a0);
                a0 = fmaf(kv.y, qv.y, a0);
                a0 = fmaf(kv.z, qv.z, a0);
                a0 = fmaf(kv.w, qv.w, a0);
            }
            #pragma unroll
            for (int kq = 16; kq < 32; ++kq) {
                float4 kv = *(const float4*)(Kt + kq * 4);
                float4 qv = *(const float4*)(qs + r * HD + kq * 4);
                a1 = fmaf(kv.x, qv.x, a1);
                a1 = fmaf(kv.y, qv.y, a1);
                a1 = fmaf(kv.z, qv.z, a1);
                a1 = fmaf(kv.w, qv.w, a1);
            }
            sc[r][tl] = (t < L) ? (a0 + a1) * scale : -3.0e38f;
        }
    }
    __syncthreads();

    // ---- chunk softmax (unnormalized): m, p=exp(s-m), l=sum p ----------
    const int h = tid >> 7, idx = tid & 127;
    {
        float mx = -3.0e38f;
        for (int tl = idx; tl < CH; tl += 128) mx = fmaxf(mx, sc[h][tl]);
        #pragma unroll
        for (int o = 32; o > 0; o >>= 1) mx = fmaxf(mx, __shfl_xor(mx, o, 64));
        if (lane == 0) wred[wave] = mx;
        __syncthreads();
        if (tid < 4) m_sh[tid] = fmaxf(wred[2 * tid], wred[2 * tid + 1]);
        __syncthreads();
        float m = m_sh[h];
        float ssum = 0.f;
        for (int tl = idx; tl < CH; tl += 128) {
            float sv = sc[h][tl];
            float p = (sv > -1.0e37f) ? __expf(sv - m) : 0.f;
            sc[h][tl] = p;
            ssum += p;
        }
        #pragma unroll
        for (int o = 32; o > 0; o >>= 1) ssum += __shfl_xor(ssum, o, 64);
        if (lane == 0) wred[wave] = ssum;
        __syncthreads();
        if (tid < 4) l_sh[tid] = wred[2 * tid] + wred[2 * tid + 1];
        __syncthreads();
    }

    // ---- pass 2: P . V, float4 V loads (was scalar: the latency killer) -
    {
        const int hp = tid >> 7;            // head
        const int tc = (tid >> 5) & 3;      // t sub-chunk (CH/4 = 128 each)
        const int dq = tid & 31;            // float4 column
        const float* Vb = v_cache + ((long)b * MAXS * HKV + g) * HD + dq * 4;
        float4 a = make_float4(0.f, 0.f, 0.f, 0.f);
        const int tl0 = tc * (CH / 4);
        #pragma unroll 8
        for (int i = 0; i < CH / 4; ++i) {
            int tl = tl0 + i;
            float p = sc[hp][tl];           // broadcast within half-wave
            float4 v = *(const float4*)(Vb + (long)(tbeg + tl) * (HKV * HD));
            a.x = fmaf(p, v.x, a.x);
            a.y = fmaf(p, v.y, a.y);
            a.z = fmaf(p, v.z, a.z);
            a.w = fmaf(p, v.w, a.w);
        }
        *(float4*)&outred[(hp * 4 + tc) * HD + dq * 4] = a;
    }
    __syncthreads();
    {
        const int d = tid & 127;
        float o = outred[(h * 4 + 0) * HD + d] + outred[(h * 4 + 1) * HD + d]
                + outred[(h * 4 + 2) * HD + d] + outred[(h * 4 + 3) * HD + d];
        long po = ((((long)b * HKV + g) * TSPLIT + ts) * 4 + h) * HD + d;
        part_o[po] = o;
        if (d == 0)
            part_ml[(((long)b * HKV + g) * TSPLIT + ts) * 4 + h] =
                make_float2(m_sh[h], l_sh[h]);
    }
}

// ---------------------------------------------------------------------------
// Combine TSPLIT partials:  out = sum_ts e^{m_ts-M} O_ts / sum_ts e^{m_ts-M} l_ts
// ---------------------------------------------------------------------------
__global__ __launch_bounds__(512)
void attention_combine(const float* __restrict__ part_o,
                       const float2* __restrict__ part_ml,
                       float* __restrict__ attn)
{
    const int g = blockIdx.x, b = blockIdx.y;
    const int h = threadIdx.x >> 7, d = threadIdx.x & 127;
    const float2* ml = part_ml + ((long)b * HKV + g) * TSPLIT * 4 + h;
    float M = -3.0e38f;
    #pragma unroll
    for (int ts = 0; ts < TSPLIT; ++ts) M = fmaxf(M, ml[ts * 4].x);
    const float* po = part_o + (((long)b * HKV + g) * TSPLIT * 4 + h) * HD + d;
    float num = 0.f, denom = 0.f;
    #pragma unroll
    for (int ts = 0; ts < TSPLIT; ++ts) {
        float2 mlv = ml[ts * 4];
        float w = (mlv.x > -1.0e37f) ? __expf(mlv.x - M) : 0.f;
        denom += mlv.y * w;
        num   += po[(long)ts * 4 * HD] * w;
    }
    attn[(long)b * DIM + g * 4 * HD + h * HD + d] = num / denom;
}

// ---------------------------------------------------------------------------
extern "C" void kernel_launch(void* const* d_in, const int* in_sizes, int n_in,
                              void* d_out, int out_size, void* d_ws, size_t ws_size,
                              hipStream_t stream)
{
    const float* x    = (const float*)d_in[0];
    const float* fcos = (const float*)d_in[1];
    const float* fsin = (const float*)d_in[2];
    const float* wq   = (const float*)d_in[3];
    const float* wk   = (const float*)d_in[4];
    const float* wv   = (const float*)d_in[5];
    const float* wo   = (const float*)d_in[6];
    float* k_cache    = (float*)d_in[7];
    float* v_cache    = (float*)d_in[8];
    const int* sp     = (const int*)d_in[9];
    float* out        = (float*)d_out;

    float* q_buf = (float*)d_ws;                 // 131072 floats
    float* k_new = q_buf + NB * DIM;             // 32768
    float* v_new = k_new + NB * HKV * HD;        // 32768
    float* attn  = v_new + NB * HKV * HD;        // 131072 (no zeroing needed)
    float* part_o = attn + NB * DIM;             // NB*HKV*TSPLIT*4*HD = 524288
    float2* part_ml = (float2*)(part_o + (long)NB * HKV * TSPLIT * 4 * HD); // 4096 f2

    // zero atomic targets (q_buf, k_new, v_new) and d_out
    hipMemsetAsync(d_ws, 0, (size_t)(NB * DIM + 2 * NB * HKV * HD) * 4, stream);
    hipMemsetAsync(d_out, 0, (size_t)NB * DIM * 4, stream);

    // KSPLIT raised: wq/wo 4->8 (2 blocks/CU, tile-load/compute overlap across
    // blocks), wk/wv 4->16 (64 -> 256 blocks: all CUs busy).
    gemv32<<<dim3(64, 8), 256, 0, stream>>>(wq, x, q_buf, DIM, DIM);
    gemv32<<<dim3(16, 16), 256, 0, stream>>>(wk, x, k_new, DIM, HKV * HD);
    gemv32<<<dim3(16, 16), 256, 0, stream>>>(wv, x, v_new, DIM, HKV * HD);
    rope_scatter<<<256, 256, 0, stream>>>(q_buf, k_new, v_new, k_cache, v_cache,
                                          fcos, fsin, sp);
    attention_part<<<dim3(HKV, NB, TSPLIT), 512, 0, stream>>>(
        q_buf, k_cache, v_cache, part_o, part_ml, sp);
    attention_combine<<<dim3(HKV, NB), 512, 0, stream>>>(part_o, part_ml, attn);
    gemv32<<<dim3(64, 8), 256, 0, stream>>>(wo, attn, out, DIM, DIM);
}